// Round 1
// baseline (52298.474 us; speedup 1.0000x reference)
//
#include <hip/hip_runtime.h>

// LSTM B=64, S=512, D=H=1024. Persistent 256-block kernel, weight-stationary
// in VGPRs (bf16 MFMA fragments), per-step: LDS-stage [x_t|h] slice -> MFMA
// partial GEMM -> global fp32 partials -> tree barrier -> owner reduce +
// gates -> h broadcast -> tree barrier. c-state lives in registers all 512
// steps. Workspace: 1KB counters + 128KB h ring (bf16) + 8MB partials.

typedef short short8 __attribute__((ext_vector_type(8)));
typedef float float4v __attribute__((ext_vector_type(4)));

#define LDSTRIDE 264   // 256 + 8 shorts pad: ds_read_b128 <=2-way bank alias (free)

__device__ __forceinline__ short f2bf(float f) {
  union { float f; unsigned u; } v; v.f = f;
  unsigned r = (v.u + 0x7fffu + ((v.u >> 16) & 1u)) >> 16;  // RNE
  return (short)r;
}

__device__ __forceinline__ float sigm(float z) {
  float e = __expf(-fabsf(z));
  float p = 1.0f / (1.0f + e);
  return z >= 0.0f ? p : 1.0f - p;
}

__device__ __forceinline__ float tanh_s(float z) {
  float e = __expf(-2.0f * fabsf(z));
  float r = (1.0f - e) / (1.0f + e);
  return z >= 0.0f ? r : -r;
}

// Monotonic two-level tree barrier. cnt[0]=release, cnt[8]=root, cnt[16+16g]=group g.
// Groups by (bid&7) so a group's 32 blocks tend to share an XCD (dispatch round-robin).
__device__ __forceinline__ void gridbar(unsigned* cnt, unsigned target, int bid, int tid) {
  __threadfence();   // release: make partial/h stores device-visible (L2 wb)
  __syncthreads();   // all threads of block done before we arrive
  if (tid == 0) {
    unsigned g = (unsigned)(bid & 7);
    unsigned a = atomicAdd(&cnt[16 + g * 16], 1u);
    if ((a & 31u) == 31u) {                 // last arrival of this group, this phase
      unsigned r = atomicAdd(&cnt[8], 1u);
      if ((r & 7u) == 7u) {                 // last group
        __hip_atomic_store(&cnt[0], target, __ATOMIC_RELEASE, __HIP_MEMORY_SCOPE_AGENT);
      }
    }
    while (__hip_atomic_load(&cnt[0], __ATOMIC_RELAXED, __HIP_MEMORY_SCOPE_AGENT) < target) {
      __builtin_amdgcn_s_sleep(2);
    }
  }
  __syncthreads();
  __builtin_amdgcn_fence(__ATOMIC_ACQUIRE, "agent");  // invalidate caches before remote reads
}

__global__ __launch_bounds__(256, 1) void lstm_persist(
    const float* __restrict__ x, const float* __restrict__ Wx,
    const float* __restrict__ bx, const float* __restrict__ Wh,
    const float* __restrict__ bh, float* __restrict__ out,
    unsigned* cnt, short* hbuf, float* partial)
{
  __shared__ short Alds[64 * LDSTRIDE];  // 33792 B

  const int tid  = threadIdx.x;
  const int bid  = blockIdx.x;
  const int kg   = bid & 7;    // K-group: 0..3 -> x cols, 4..7 -> h cols (256 each)
  const int ng   = bid >> 3;   // N-group: 128 permuted gate rows
  const int lane = tid & 63;
  const int w    = tid >> 6;   // wave 0..3
  const int l15  = lane & 15;
  const int lh   = lane >> 4;  // 0..3

  // ---- static weight B-fragments in VGPRs: bw[nt][ks], wave w owns rows [32w,32w+32) of group ----
  short8 bw[2][8];
  {
    const float* Wsrc = (kg < 4) ? Wx : Wh;
    const int kb = (kg & 3) * 256;
    #pragma unroll
    for (int nt = 0; nt < 2; ++nt) {
      const int n_local = (2 * w + nt) * 16 + l15;   // 0..127 within group
      const int gi = n_local >> 5;                   // gate 0..3 (i,f,o,g)
      const int jp = n_local & 31;
      const float* rp = Wsrc + (size_t)(gi * 1024 + ng * 32 + jp) * 1024 + kb;
      #pragma unroll
      for (int ks = 0; ks < 8; ++ks) {
        const int k0 = ks * 32 + lh * 8;
        float4v v0 = *(const float4v*)(rp + k0);
        float4v v1 = *(const float4v*)(rp + k0 + 4);
        short8 o;
        o[0]=f2bf(v0[0]); o[1]=f2bf(v0[1]); o[2]=f2bf(v0[2]); o[3]=f2bf(v0[3]);
        o[4]=f2bf(v1[0]); o[5]=f2bf(v1[1]); o[6]=f2bf(v1[2]); o[7]=f2bf(v1[3]);
        bw[nt][ks] = o;
      }
    }
  }

  // ---- reduce-phase identity: this block owns h[:, 4*bid .. 4*bid+4) ----
  const int rb  = tid >> 2;           // batch 0..63
  const int jj  = tid & 3;
  const int jg  = bid * 4 + jj;       // hidden index 0..1023
  const int ngr = bid >> 3;
  const int nlj = (bid & 7) * 4 + jj; // j' within N-group (0..31)
  float bias[4];
  #pragma unroll
  for (int gi = 0; gi < 4; ++gi)
    bias[gi] = bx[gi * 1024 + jg] + bh[gi * 1024 + jg];

  float c_reg = 0.0f, h_keep = 0.0f;

  const int sb = tid >> 2;  // staging batch
  const int q  = tid & 3;   // staging k-quarter (64 elems)

  for (int t = 0; t < 512; ++t) {
    // ---- stage dynamic A-slice (64 x 256 bf16) into LDS ----
    short* dst = &Alds[sb * LDSTRIDE + q * 64];
    if (kg < 4) {
      const float* src = x + ((size_t)sb * 512 + t) * 1024 + kg * 256 + q * 64;
      #pragma unroll
      for (int i = 0; i < 8; ++i) {
        float4v v0 = ((const float4v*)src)[2 * i];
        float4v v1 = ((const float4v*)src)[2 * i + 1];
        short8 o;
        o[0]=f2bf(v0[0]); o[1]=f2bf(v0[1]); o[2]=f2bf(v0[2]); o[3]=f2bf(v0[3]);
        o[4]=f2bf(v1[0]); o[5]=f2bf(v1[1]); o[6]=f2bf(v1[2]); o[7]=f2bf(v1[3]);
        ((short8*)dst)[i] = o;
      }
    } else {
      const short* src = hbuf + sb * 1024 + (kg - 4) * 256 + q * 64;
      #pragma unroll
      for (int i = 0; i < 8; ++i)
        ((short8*)dst)[i] = ((const short8*)src)[i];
    }
    __syncthreads();

    // ---- GEMM: D[batch 64][rows 32 per wave] over K=256 ----
    float4v acc[4][2];
    #pragma unroll
    for (int mt = 0; mt < 4; ++mt)
      #pragma unroll
      for (int nt = 0; nt < 2; ++nt)
        acc[mt][nt] = (float4v){0.f, 0.f, 0.f, 0.f};
    #pragma unroll
    for (int ks = 0; ks < 8; ++ks) {
      short8 af[4];
      #pragma unroll
      for (int mt = 0; mt < 4; ++mt)
        af[mt] = *(const short8*)&Alds[(mt * 16 + l15) * LDSTRIDE + ks * 32 + lh * 8];
      #pragma unroll
      for (int mt = 0; mt < 4; ++mt)
        #pragma unroll
        for (int nt = 0; nt < 2; ++nt)
          acc[mt][nt] = __builtin_amdgcn_mfma_f32_16x16x32_bf16(
              af[mt], bw[nt][ks], acc[mt][nt], 0, 0, 0);
    }

    // ---- store fp32 partials: layout [kg][ng][b 64][nl 128] ----
    float* pb = partial + (size_t)(kg * 32 + ng) * 8192;
    #pragma unroll
    for (int mt = 0; mt < 4; ++mt) {
      #pragma unroll
      for (int nt = 0; nt < 2; ++nt) {
        const int nl = (2 * w + nt) * 16 + l15;
        const int b0 = mt * 16 + lh * 4;
        #pragma unroll
        for (int r = 0; r < 4; ++r)
          pb[(b0 + r) * 128 + nl] = acc[mt][nt][r];
      }
    }

    gridbar(cnt, 2u * (unsigned)t + 1u, bid, tid);

    // ---- reduce 8 K-partials + bias, gates, state update ----
    float s0 = bias[0], s1 = bias[1], s2 = bias[2], s3 = bias[3];
    const float* pr = partial + (size_t)(ngr * 64 + rb) * 128 + nlj;
    #pragma unroll
    for (int kgi = 0; kgi < 8; ++kgi) {
      const float* p = pr + (size_t)kgi * 32 * 8192;
      s0 += p[0]; s1 += p[32]; s2 += p[64]; s3 += p[96];
    }
    const float igate = sigm(s0);
    const float fgate = sigm(s1);
    const float ogate = sigm(s2);
    const float ggate = tanh_s(s3);
    c_reg = fgate * c_reg + igate * ggate;
    const float hh = ogate * tanh_s(c_reg);
    h_keep = hh;
    out[((size_t)rb * 512 + t) * 1024 + jg] = hh;       // outputs[b][t][j]
    hbuf[rb * 1024 + jg] = f2bf(hh);                    // bf16 h for next step

    gridbar(cnt, 2u * (unsigned)t + 2u, bid, tid);
  }

  const size_t BSH = (size_t)64 * 512 * 1024;
  out[BSH + (size_t)rb * 1024 + jg] = h_keep;           // h_last
  out[BSH + 65536 + (size_t)rb * 1024 + jg] = c_reg;    // c_last
}

extern "C" void kernel_launch(void* const* d_in, const int* in_sizes, int n_in,
                              void* d_out, int out_size, void* d_ws, size_t ws_size,
                              hipStream_t stream) {
  (void)in_sizes; (void)n_in; (void)out_size; (void)ws_size;
  const float* x  = (const float*)d_in[0];
  const float* Wx = (const float*)d_in[1];
  const float* bx = (const float*)d_in[2];
  const float* Wh = (const float*)d_in[3];
  const float* bh = (const float*)d_in[4];
  float* out = (float*)d_out;

  unsigned* cnt  = (unsigned*)d_ws;                         // 1 KB counters
  short* hbuf    = (short*)((char*)d_ws + 1024);            // 128 KB bf16 h
  float* partial = (float*)((char*)d_ws + 1024 + 131072);   // 8 MB fp32 partials

  // zero barrier counters + h0 (ws is poisoned 0xAA before every launch)
  hipMemsetAsync(d_ws, 0, 1024 + 131072, stream);

  hipLaunchKernelGGL(lstm_persist, dim3(256), dim3(256), 0, stream,
                     x, Wx, bx, Wh, bh, out, cnt, hbuf, partial);
}

// Round 2
// 34817.731 us; speedup vs baseline: 1.5021x; 1.5021x over previous
//
#include <hip/hip_runtime.h>

// LSTM B=64, S=512, D=H=1024. Persistent 256-block x 512-thread kernel.
// No K-split partials: each block owns 16 gate-rows (4 j x 4 gates) with
// FULL K=2048 weights in VGPRs (K quartered across waves, 64 VGPR/thr).
// Per step: waves read A-frags ([x_t|h] bf16) straight from global (L2),
// MFMA, 4-way K-reduce in LDS, gates+state locally (c in regs), write bf16
// h double-buffered, ONE grid barrier per step. x pre-converted to bf16
// [t][b][d] once if ws_size allows, else fp32 read inline (template).

typedef short short8 __attribute__((ext_vector_type(8)));
typedef float float4v __attribute__((ext_vector_type(4)));

__device__ __forceinline__ short f2bf(float f) {
  union { float f; unsigned u; } v; v.f = f;
  unsigned r = (v.u + 0x7fffu + ((v.u >> 16) & 1u)) >> 16;  // RNE
  return (short)r;
}

__device__ __forceinline__ float sigm(float z) {
  float e = __expf(-fabsf(z));
  float p = 1.0f / (1.0f + e);
  return z >= 0.0f ? p : 1.0f - p;
}

__device__ __forceinline__ float tanh_s(float z) {
  float e = __expf(-2.0f * fabsf(z));
  float r = (1.0f - e) / (1.0f + e);
  return z >= 0.0f ? r : -r;
}

// Monotonic two-level tree barrier. cnt[0]=release, cnt[8]=root, cnt[16+16g]=group g.
__device__ __forceinline__ void gridbar(unsigned* cnt, unsigned target, int bid, int tid) {
  __threadfence();   // release: h stores device-visible
  __syncthreads();
  if (tid == 0) {
    unsigned g = (unsigned)(bid & 7);
    unsigned a = atomicAdd(&cnt[16 + g * 16], 1u);
    if ((a & 31u) == 31u) {
      unsigned r = atomicAdd(&cnt[8], 1u);
      if ((r & 7u) == 7u) {
        __hip_atomic_store(&cnt[0], target, __ATOMIC_RELEASE, __HIP_MEMORY_SCOPE_AGENT);
      }
    }
    while (__hip_atomic_load(&cnt[0], __ATOMIC_RELAXED, __HIP_MEMORY_SCOPE_AGENT) < target) {
      __builtin_amdgcn_s_sleep(2);
    }
  }
  __syncthreads();
  __builtin_amdgcn_fence(__ATOMIC_ACQUIRE, "agent");
}

// one-time x fp32 [b][s][d] -> bf16 [s][b][d]
__global__ __launch_bounds__(256) void xconv(const float* __restrict__ x,
                                             short* __restrict__ xbf) {
  const int gid = blockIdx.x * 256 + threadIdx.x;
  const long i8 = (long)gid * 8;
  const int d  = (int)(i8 & 1023);
  const int bs = (int)(i8 >> 10);
  const int s  = bs & 511;
  const int b  = bs >> 9;
  const float4v* src = (const float4v*)(x + i8);
  float4v v0 = src[0], v1 = src[1];
  short8 o;
  o[0]=f2bf(v0[0]); o[1]=f2bf(v0[1]); o[2]=f2bf(v0[2]); o[3]=f2bf(v0[3]);
  o[4]=f2bf(v1[0]); o[5]=f2bf(v1[1]); o[6]=f2bf(v1[2]); o[7]=f2bf(v1[3]);
  *(short8*)(xbf + (((size_t)(s * 64 + b)) << 10) + d) = o;
}

template <bool XBF>
__global__ __launch_bounds__(512, 2) void lstm_persist(
    const float* __restrict__ x, const short* __restrict__ xbf,
    const float* __restrict__ Wx, const float* __restrict__ bx,
    const float* __restrict__ Wh, const float* __restrict__ bh,
    float* __restrict__ out, unsigned* cnt, short* hbuf)
{
  __shared__ float red[4][64][16];  // [kq][batch][n]  16 KB

  const int tid  = threadIdx.x;
  const int bid  = blockIdx.x;     // j-slice 0..255
  const int lane = tid & 63;
  const int w    = tid >> 6;       // wave 0..7
  const int kq   = w & 3;          // K-quarter: 0,1 -> x cols, 2,3 -> h cols
  const int mh   = w >> 2;         // batch half
  const int l15  = lane & 15;
  const int lh   = lane >> 4;

  // ---- static weights: rows n=0..15, n = jj*4+gi; lane l15 = n ----
  // lane holds W[row(n)][kq*512 + ks*32 + lh*8 + (0..7)] as bf16 B-frags
  short8 bw[16];
  {
    const int n   = l15;
    const int gi  = n & 3;
    const int jj  = n >> 2;
    const int row = gi * 1024 + bid * 4 + jj;
    const float* Wsrc = (kq < 2) ? (Wx + (size_t)row * 1024 + kq * 512)
                                 : (Wh + (size_t)row * 1024 + (kq - 2) * 512);
    #pragma unroll
    for (int ks = 0; ks < 16; ++ks) {
      const float* p = Wsrc + ks * 32 + lh * 8;
      float4v v0 = *(const float4v*)p;
      float4v v1 = *(const float4v*)(p + 4);
      short8 o;
      o[0]=f2bf(v0[0]); o[1]=f2bf(v0[1]); o[2]=f2bf(v0[2]); o[3]=f2bf(v0[3]);
      o[4]=f2bf(v1[0]); o[5]=f2bf(v1[1]); o[6]=f2bf(v1[2]); o[7]=f2bf(v1[3]);
      bw[ks] = o;
    }
  }

  // ---- epilogue identity: tid<256 owns (batch eb, hidden ej) ----
  const int eb  = tid >> 2;
  const int ejj = tid & 3;
  const int ej  = bid * 4 + ejj;
  float bias[4] = {0.f, 0.f, 0.f, 0.f};
  if (tid < 256) {
    #pragma unroll
    for (int gi = 0; gi < 4; ++gi) bias[gi] = bx[gi * 1024 + ej] + bh[gi * 1024 + ej];
  }
  float c_reg = 0.0f, h_keep = 0.0f;

  short* hb0 = hbuf;
  short* hb1 = hbuf + 65536;

  for (int t = 0; t < 512; ++t) {
    float4v acc[2];
    acc[0] = (float4v){0.f, 0.f, 0.f, 0.f};
    acc[1] = (float4v){0.f, 0.f, 0.f, 0.f};

    if (XBF || kq >= 2) {
      // bf16 A: x (pre-converted) or h ring. layout [b][1024]
      const short* Ab = (kq < 2)
          ? (xbf + ((size_t)t << 16) + kq * 512 + lh * 8)
          : (((t & 1) ? hb1 : hb0) + (kq - 2) * 512 + lh * 8);
      #pragma unroll
      for (int ks = 0; ks < 16; ++ks) {
        #pragma unroll
        for (int mt = 0; mt < 2; ++mt) {
          const int b = mh * 32 + mt * 16 + l15;
          short8 a = *(const short8*)(Ab + ((size_t)b << 10) + ks * 32);
          acc[mt] = __builtin_amdgcn_mfma_f32_16x16x32_bf16(a, bw[ks], acc[mt], 0, 0, 0);
        }
      }
    } else {
      // fp32 x fallback: x[b][t][k], convert inline
      const float* Ab = x + (size_t)t * 1024 + kq * 512 + lh * 8;
      #pragma unroll
      for (int ks = 0; ks < 16; ++ks) {
        #pragma unroll
        for (int mt = 0; mt < 2; ++mt) {
          const int b = mh * 32 + mt * 16 + l15;
          const float* p = Ab + (size_t)b * 524288 + ks * 32;
          float4v v0 = *(const float4v*)p;
          float4v v1 = *(const float4v*)(p + 4);
          short8 a;
          a[0]=f2bf(v0[0]); a[1]=f2bf(v0[1]); a[2]=f2bf(v0[2]); a[3]=f2bf(v0[3]);
          a[4]=f2bf(v1[0]); a[5]=f2bf(v1[1]); a[6]=f2bf(v1[2]); a[7]=f2bf(v1[3]);
          acc[mt] = __builtin_amdgcn_mfma_f32_16x16x32_bf16(a, bw[ks], acc[mt], 0, 0, 0);
        }
      }
    }

    // ---- in-block K-reduce via LDS ----
    #pragma unroll
    for (int mt = 0; mt < 2; ++mt)
      #pragma unroll
      for (int r = 0; r < 4; ++r)
        red[kq][mh * 32 + mt * 16 + lh * 4 + r][l15] = acc[mt][r];
    __syncthreads();

    if (tid < 256) {
      float4v r0 = *(const float4v*)&red[0][eb][ejj * 4];
      float4v r1 = *(const float4v*)&red[1][eb][ejj * 4];
      float4v r2 = *(const float4v*)&red[2][eb][ejj * 4];
      float4v r3 = *(const float4v*)&red[3][eb][ejj * 4];
      const float s0 = r0[0] + r1[0] + r2[0] + r3[0] + bias[0];
      const float s1 = r0[1] + r1[1] + r2[1] + r3[1] + bias[1];
      const float s2 = r0[2] + r1[2] + r2[2] + r3[2] + bias[2];
      const float s3 = r0[3] + r1[3] + r2[3] + r3[3] + bias[3];
      const float ig = sigm(s0);
      const float fg = sigm(s1);
      const float og = sigm(s2);
      const float gg = tanh_s(s3);
      c_reg = fg * c_reg + ig * gg;
      const float hh = og * tanh_s(c_reg);
      h_keep = hh;
      out[((size_t)eb * 512 + t) * 1024 + ej] = hh;
      (((t + 1) & 1) ? hb1 : hb0)[eb * 1024 + ej] = f2bf(hh);
    }

    gridbar(cnt, (unsigned)t + 1u, bid, tid);
  }

  if (tid < 256) {
    const size_t BSH = (size_t)64 * 512 * 1024;
    out[BSH + (size_t)eb * 1024 + ej] = h_keep;
    out[BSH + 65536 + (size_t)eb * 1024 + ej] = c_reg;
  }
}

extern "C" void kernel_launch(void* const* d_in, const int* in_sizes, int n_in,
                              void* d_out, int out_size, void* d_ws, size_t ws_size,
                              hipStream_t stream) {
  (void)in_sizes; (void)n_in; (void)out_size;
  const float* x  = (const float*)d_in[0];
  const float* Wx = (const float*)d_in[1];
  const float* bx = (const float*)d_in[2];
  const float* Wh = (const float*)d_in[3];
  const float* bh = (const float*)d_in[4];
  float* out = (float*)d_out;

  unsigned* cnt = (unsigned*)d_ws;                          // 1 KB counters
  short* hbuf   = (short*)((char*)d_ws + 1024);             // 2 x 128 KB h ring
  short* xbf    = (short*)((char*)d_ws + 1024 + 262144);    // 64 MB bf16 x [t][b][d]
  const size_t need_xbf = 1024u + 262144u + (size_t)64 * 512 * 1024 * 2;

  hipMemsetAsync(d_ws, 0, 1024 + 262144, stream);           // counters + h0 = 0

  if (ws_size >= need_xbf) {
    // 64*512*1024 / (256*8) = 16384 blocks
    hipLaunchKernelGGL(xconv, dim3(16384), dim3(256), 0, stream, x, xbf);
    hipLaunchKernelGGL(lstm_persist<true>, dim3(256), dim3(512), 0, stream,
                       x, xbf, Wx, bx, Wh, bh, out, cnt, hbuf);
  } else {
    hipLaunchKernelGGL(lstm_persist<false>, dim3(256), dim3(512), 0, stream,
                       x, hbuf, Wx, bx, Wh, bh, out, cnt, hbuf);
  }
}

// Round 3
// 7701.337 us; speedup vs baseline: 6.7908x; 4.5210x over previous
//
#include <hip/hip_runtime.h>

// LSTM B=64, S=512, D=H=1024. Persistent 256-block x 512-thread kernel.
// Each block owns 16 gate-rows (4 j x 4 gates) with FULL K=2048 weights in
// VGPRs (K quartered across waves). Per step: A-frags ([x_t|h]) read from
// global, MFMA, in-block LDS K-reduce, gates+state local (c in regs), bf16
// h to a double-buffered ring, ONE grid barrier per step.
// Round 3: NO cache-maintenance fences in the loop. All cross-block data
// (h ring, barrier counters) moves via relaxed AGENT-scope atomics (sc1,
// L2-bypassing, coherent at L3). x stays L2-cached across steps.

typedef short short8 __attribute__((ext_vector_type(8)));
typedef float float4v __attribute__((ext_vector_type(4)));
typedef unsigned long long u64;

__device__ __forceinline__ short f2bf(float f) {
  union { float f; unsigned u; } v; v.f = f;
  unsigned r = (v.u + 0x7fffu + ((v.u >> 16) & 1u)) >> 16;  // RNE
  return (short)r;
}

__device__ __forceinline__ float sigm(float z) {
  float e = __expf(-fabsf(z));
  float p = 1.0f / (1.0f + e);
  return z >= 0.0f ? p : 1.0f - p;
}

__device__ __forceinline__ float tanh_s(float z) {
  float e = __expf(-2.0f * fabsf(z));
  float r = (1.0f - e) / (1.0f + e);
  return z >= 0.0f ? r : -r;
}

// Fence-free monotonic tree barrier: relaxed agent atomics only.
// cnt[0]=release, cnt[8]=root, cnt[16+16g]=group g (g = bid&7).
// Visibility: __syncthreads() drains vmcnt before s_barrier, so all prior
// agent-scope stores are committed at the coherence point before arrival.
__device__ __forceinline__ void gridbar(unsigned* cnt, unsigned target, int bid, int tid) {
  __syncthreads();
  if (tid == 0) {
    unsigned g = (unsigned)(bid & 7);
    unsigned a = __hip_atomic_fetch_add(&cnt[16 + g * 16], 1u,
                    __ATOMIC_RELAXED, __HIP_MEMORY_SCOPE_AGENT);
    if ((a & 31u) == 31u) {
      unsigned r = __hip_atomic_fetch_add(&cnt[8], 1u,
                    __ATOMIC_RELAXED, __HIP_MEMORY_SCOPE_AGENT);
      if ((r & 7u) == 7u) {
        __hip_atomic_store(&cnt[0], target, __ATOMIC_RELAXED, __HIP_MEMORY_SCOPE_AGENT);
      }
    }
    while (__hip_atomic_load(&cnt[0], __ATOMIC_RELAXED, __HIP_MEMORY_SCOPE_AGENT) < target) {
      __builtin_amdgcn_s_sleep(4);
    }
  }
  __syncthreads();
}

// one-time x fp32 [b][s][d] -> bf16 [s][b][d]
__global__ __launch_bounds__(256) void xconv(const float* __restrict__ x,
                                             short* __restrict__ xbf) {
  const int gid = blockIdx.x * 256 + threadIdx.x;
  const long i8 = (long)gid * 8;
  const int d  = (int)(i8 & 1023);
  const int bs = (int)(i8 >> 10);
  const int s  = bs & 511;
  const int b  = bs >> 9;
  const float4v* src = (const float4v*)(x + i8);
  float4v v0 = src[0], v1 = src[1];
  short8 o;
  o[0]=f2bf(v0[0]); o[1]=f2bf(v0[1]); o[2]=f2bf(v0[2]); o[3]=f2bf(v0[3]);
  o[4]=f2bf(v1[0]); o[5]=f2bf(v1[1]); o[6]=f2bf(v1[2]); o[7]=f2bf(v1[3]);
  *(short8*)(xbf + (((size_t)(s * 64 + b)) << 10) + d) = o;
}

template <bool XBF>
__global__ __launch_bounds__(512, 2) void lstm_persist(
    const float* __restrict__ x, const short* __restrict__ xbf,
    const float* __restrict__ Wx, const float* __restrict__ bx,
    const float* __restrict__ Wh, const float* __restrict__ bh,
    float* __restrict__ out, unsigned* cnt, short* hbuf)
{
  __shared__ float red[4][64][16];   // [kq][batch][n]  16 KB
  __shared__ short hstage[64][4];    // bf16 h staging for pack-to-u32

  const int tid  = threadIdx.x;
  const int bid  = blockIdx.x;     // j-slice 0..255
  const int lane = tid & 63;
  const int w    = tid >> 6;       // wave 0..7
  const int kq   = w & 3;          // K-quarter: 0,1 -> x cols, 2,3 -> h cols
  const int mh   = w >> 2;         // batch half
  const int l15  = lane & 15;
  const int lh   = lane >> 4;

  // ---- static weights: rows n=0..15, n = jj*4+gi; lane l15 = n ----
  short8 bw[16];
  {
    const int n   = l15;
    const int gi  = n & 3;
    const int jj  = n >> 2;
    const int row = gi * 1024 + bid * 4 + jj;
    const float* Wsrc = (kq < 2) ? (Wx + (size_t)row * 1024 + kq * 512)
                                 : (Wh + (size_t)row * 1024 + (kq - 2) * 512);
    #pragma unroll
    for (int ks = 0; ks < 16; ++ks) {
      const float* p = Wsrc + ks * 32 + lh * 8;
      float4v v0 = *(const float4v*)p;
      float4v v1 = *(const float4v*)(p + 4);
      short8 o;
      o[0]=f2bf(v0[0]); o[1]=f2bf(v0[1]); o[2]=f2bf(v0[2]); o[3]=f2bf(v0[3]);
      o[4]=f2bf(v1[0]); o[5]=f2bf(v1[1]); o[6]=f2bf(v1[2]); o[7]=f2bf(v1[3]);
      bw[ks] = o;
    }
  }

  // ---- epilogue identity: tid<256 owns (batch eb, hidden ej) ----
  const int eb  = tid >> 2;
  const int ejj = tid & 3;
  const int ej  = bid * 4 + ejj;
  float bias[4] = {0.f, 0.f, 0.f, 0.f};
  if (tid < 256) {
    #pragma unroll
    for (int gi = 0; gi < 4; ++gi) bias[gi] = bx[gi * 1024 + ej] + bh[gi * 1024 + ej];
  }
  float c_reg = 0.0f, h_keep = 0.0f;

  short* hb0 = hbuf;
  short* hb1 = hbuf + 65536;

  for (int t = 0; t < 512; ++t) {
    float4v acc[2];
    acc[0] = (float4v){0.f, 0.f, 0.f, 0.f};
    acc[1] = (float4v){0.f, 0.f, 0.f, 0.f};

    if (kq < 2) {
      if (XBF) {
        const short* Ab = xbf + ((size_t)t << 16) + kq * 512 + lh * 8;
        #pragma unroll
        for (int ks = 0; ks < 16; ++ks) {
          #pragma unroll
          for (int mt = 0; mt < 2; ++mt) {
            const int b = mh * 32 + mt * 16 + l15;
            short8 a = *(const short8*)(Ab + ((size_t)b << 10) + ks * 32);
            acc[mt] = __builtin_amdgcn_mfma_f32_16x16x32_bf16(a, bw[ks], acc[mt], 0, 0, 0);
          }
        }
      } else {
        const float* Ab = x + (size_t)t * 1024 + kq * 512 + lh * 8;
        #pragma unroll
        for (int ks = 0; ks < 16; ++ks) {
          #pragma unroll
          for (int mt = 0; mt < 2; ++mt) {
            const int b = mh * 32 + mt * 16 + l15;
            const float* p = Ab + (size_t)b * 524288 + ks * 32;
            float4v v0 = *(const float4v*)p;
            float4v v1 = *(const float4v*)(p + 4);
            short8 a;
            a[0]=f2bf(v0[0]); a[1]=f2bf(v0[1]); a[2]=f2bf(v0[2]); a[3]=f2bf(v0[3]);
            a[4]=f2bf(v1[0]); a[5]=f2bf(v1[1]); a[6]=f2bf(v1[2]); a[7]=f2bf(v1[3]);
            acc[mt] = __builtin_amdgcn_mfma_f32_16x16x32_bf16(a, bw[ks], acc[mt], 0, 0, 0);
          }
        }
      }
    } else {
      // h via relaxed agent atomics (L2-bypassing, coherent at L3)
      const short* hb = (t & 1) ? hb1 : hb0;
      const int base = (kq - 2) * 512 + lh * 8;
      #pragma unroll
      for (int ks = 0; ks < 16; ++ks) {
        #pragma unroll
        for (int mt = 0; mt < 2; ++mt) {
          const int b = mh * 32 + mt * 16 + l15;
          const u64* p = (const u64*)(hb + ((size_t)b << 10) + base + ks * 32);
          union { u64 q[2]; short8 s; } u;
          u.q[0] = __hip_atomic_load(p,     __ATOMIC_RELAXED, __HIP_MEMORY_SCOPE_AGENT);
          u.q[1] = __hip_atomic_load(p + 1, __ATOMIC_RELAXED, __HIP_MEMORY_SCOPE_AGENT);
          acc[mt] = __builtin_amdgcn_mfma_f32_16x16x32_bf16(u.s, bw[ks], acc[mt], 0, 0, 0);
        }
      }
    }

    // ---- in-block K-reduce via LDS ----
    #pragma unroll
    for (int mt = 0; mt < 2; ++mt)
      #pragma unroll
      for (int r = 0; r < 4; ++r)
        red[kq][mh * 32 + mt * 16 + lh * 4 + r][l15] = acc[mt][r];
    __syncthreads();

    if (tid < 256) {
      float4v r0 = *(const float4v*)&red[0][eb][ejj * 4];
      float4v r1 = *(const float4v*)&red[1][eb][ejj * 4];
      float4v r2 = *(const float4v*)&red[2][eb][ejj * 4];
      float4v r3 = *(const float4v*)&red[3][eb][ejj * 4];
      const float s0 = r0[0] + r1[0] + r2[0] + r3[0] + bias[0];
      const float s1 = r0[1] + r1[1] + r2[1] + r3[1] + bias[1];
      const float s2 = r0[2] + r1[2] + r2[2] + r3[2] + bias[2];
      const float s3 = r0[3] + r1[3] + r2[3] + r3[3] + bias[3];
      const float ig = sigm(s0);
      const float fg = sigm(s1);
      const float og = sigm(s2);
      const float gg = tanh_s(s3);
      c_reg = fg * c_reg + ig * gg;
      const float hh = og * tanh_s(c_reg);
      h_keep = hh;
      out[((size_t)eb * 512 + t) * 1024 + ej] = hh;
      hstage[eb][ejj] = f2bf(hh);
    }
    __syncthreads();

    // pack 2 bf16 -> one u32 agent-scope store into next h buffer
    if (tid < 128) {
      unsigned v = ((const unsigned*)hstage)[tid];
      const int eb2 = tid >> 1;
      const int j0  = bid * 4 + (tid & 1) * 2;
      short* hbn = ((t + 1) & 1) ? hb1 : hb0;
      __hip_atomic_store((unsigned*)(hbn + eb2 * 1024 + j0), v,
                         __ATOMIC_RELAXED, __HIP_MEMORY_SCOPE_AGENT);
    }

    gridbar(cnt, (unsigned)t + 1u, bid, tid);
  }

  if (tid < 256) {
    const size_t BSH = (size_t)64 * 512 * 1024;
    out[BSH + (size_t)eb * 1024 + ej] = h_keep;
    out[BSH + 65536 + (size_t)eb * 1024 + ej] = c_reg;
  }
}

extern "C" void kernel_launch(void* const* d_in, const int* in_sizes, int n_in,
                              void* d_out, int out_size, void* d_ws, size_t ws_size,
                              hipStream_t stream) {
  (void)in_sizes; (void)n_in; (void)out_size;
  const float* x  = (const float*)d_in[0];
  const float* Wx = (const float*)d_in[1];
  const float* bx = (const float*)d_in[2];
  const float* Wh = (const float*)d_in[3];
  const float* bh = (const float*)d_in[4];
  float* out = (float*)d_out;

  unsigned* cnt = (unsigned*)d_ws;                          // 1 KB counters
  short* hbuf   = (short*)((char*)d_ws + 1024);             // 2 x 128 KB h ring
  short* xbf    = (short*)((char*)d_ws + 1024 + 262144);    // 64 MB bf16 x [t][b][d]
  const size_t need_xbf = 1024u + 262144u + (size_t)64 * 512 * 1024 * 2;

  hipMemsetAsync(d_ws, 0, 1024 + 262144, stream);           // counters + h0 = 0

  if (ws_size >= need_xbf) {
    hipLaunchKernelGGL(xconv, dim3(16384), dim3(256), 0, stream, x, xbf);
    hipLaunchKernelGGL(lstm_persist<true>, dim3(256), dim3(512), 0, stream,
                       x, xbf, Wx, bx, Wh, bh, out, cnt, hbuf);
  } else {
    hipLaunchKernelGGL(lstm_persist<false>, dim3(256), dim3(512), 0, stream,
                       x, hbuf, Wx, bx, Wh, bh, out, cnt, hbuf);
  }
}